// Round 9
// baseline (129482.251 us; speedup 1.0000x reference)
//
#include <hip/hip_runtime.h>
#include <hip/hip_bf16.h>
#include <stdint.h>

// GRU-style LanguageEncoder: T=64, B=256, VOCAB=32000, D=512, H=1024.
// Reference semantics: a = tanh(a_x + (r * h) @ w_h_a + b_a)  ((r*h) BEFORE matmul).
// k_recur history (per-step us): R2 33; R3 21.5; R6 16.4; R8 12.8; R9/R10 12.4;
// R11 FAIL; R12 null; R13 null; R14 11.3 (best); R15 13.2 REG; R16 11.4 null;
// R17 BUILD FAIL; R18 12.7 REG (32-burst load queueing).
// Ledger: read path/volume, write class, poll mechanics, load pipelining - all
// null or regression. The invariant floor is the WRITE-VISIBILITY + DETECT
// chain through the DIE-LEVEL coherence point (WRITE_SIZE 67.6MB = exchange
// write-through to DRAM), executed 128x. Every variant kept sync groups
// spanning TWO XCDs (grid mg+4*jb -> peers on XCDs {mg, mg+4}).
// R19: XCD-PURE sync groups. 8 m-groups x 32 batch rows; group = 32 blocks x
// 32 cols; grid (8,32), linear id x+8y -> XCD x (R12-measured, runtime-
// verified via xtab). All exchange/flags/loads within a group use sc0 ONLY:
// the XCD L2 is the coherence point -> no DRAM write-through, no cross-die
// detect, L2-latency chain. No rotation needed (sc0 bypasses L1; L2 fresh).
// Per-block 32 cols: W_zr (64x1032 bf16 = 129KB) in LDS; W_a streamed from
// L2 each A-phase (immutable, 2MB/XCD resident) with depth-1 chunk pipeline.
// If a group is not XCD-pure at runtime -> all-sc0sc1 fallback (R13-proven).

#define TT 64
#define BB 256
#define DD 512
#define HH 1024
#define N3H 3072

using frag  = __attribute__((ext_vector_type(8))) short;   // 8 bf16 (4 VGPRs)
using f32x4 = __attribute__((ext_vector_type(4))) float;   // MFMA accumulator

__device__ __forceinline__ uint16_t f2b(float f) {
    uint32_t u = __builtin_bit_cast(uint32_t, f);
    uint32_t r = u + 0x7FFFu + ((u >> 16) & 1u);   // round-to-nearest-even
    return (uint16_t)(r >> 16);
}
__device__ __forceinline__ float b2f(uint16_t b) {
    uint32_t u = ((uint32_t)b) << 16;
    return __builtin_bit_cast(float, u);
}

// ---- 8 x 16B loads, 64B-strided, no wait (counted vmcnt via WAIT8) ----
// gfx950 asm operand order: offset:N BEFORE cache flags.
__device__ __forceinline__ void load8_l2(const uint16_t* p, frag* f) {   // sc0: L1-bypass, L2-served
    asm volatile(
        "global_load_dwordx4 %0, %8, off sc0\n\t"
        "global_load_dwordx4 %1, %8, off offset:64 sc0\n\t"
        "global_load_dwordx4 %2, %8, off offset:128 sc0\n\t"
        "global_load_dwordx4 %3, %8, off offset:192 sc0\n\t"
        "global_load_dwordx4 %4, %8, off offset:256 sc0\n\t"
        "global_load_dwordx4 %5, %8, off offset:320 sc0\n\t"
        "global_load_dwordx4 %6, %8, off offset:384 sc0\n\t"
        "global_load_dwordx4 %7, %8, off offset:448 sc0"
        : "=&v"(f[0]), "=&v"(f[1]), "=&v"(f[2]), "=&v"(f[3]),
          "=&v"(f[4]), "=&v"(f[5]), "=&v"(f[6]), "=&v"(f[7])
        : "v"(p) : "memory");
}
__device__ __forceinline__ void load8_l3(const uint16_t* p, frag* f) {   // sc0sc1: coherence point
    asm volatile(
        "global_load_dwordx4 %0, %8, off sc0 sc1\n\t"
        "global_load_dwordx4 %1, %8, off offset:64 sc0 sc1\n\t"
        "global_load_dwordx4 %2, %8, off offset:128 sc0 sc1\n\t"
        "global_load_dwordx4 %3, %8, off offset:192 sc0 sc1\n\t"
        "global_load_dwordx4 %4, %8, off offset:256 sc0 sc1\n\t"
        "global_load_dwordx4 %5, %8, off offset:320 sc0 sc1\n\t"
        "global_load_dwordx4 %6, %8, off offset:384 sc0 sc1\n\t"
        "global_load_dwordx4 %7, %8, off offset:448 sc0 sc1"
        : "=&v"(f[0]), "=&v"(f[1]), "=&v"(f[2]), "=&v"(f[3]),
          "=&v"(f[4]), "=&v"(f[5]), "=&v"(f[6]), "=&v"(f[7])
        : "v"(p) : "memory");
}
__device__ __forceinline__ void load8_c(const uint16_t* p, frag* f) {    // cached (immutable wht)
    asm volatile(
        "global_load_dwordx4 %0, %8, off\n\t"
        "global_load_dwordx4 %1, %8, off offset:64\n\t"
        "global_load_dwordx4 %2, %8, off offset:128\n\t"
        "global_load_dwordx4 %3, %8, off offset:192\n\t"
        "global_load_dwordx4 %4, %8, off offset:256\n\t"
        "global_load_dwordx4 %5, %8, off offset:320\n\t"
        "global_load_dwordx4 %6, %8, off offset:384\n\t"
        "global_load_dwordx4 %7, %8, off offset:448"
        : "=&v"(f[0]), "=&v"(f[1]), "=&v"(f[2]), "=&v"(f[3]),
          "=&v"(f[4]), "=&v"(f[5]), "=&v"(f[6]), "=&v"(f[7])
        : "v"(p) : "memory");
}

// counted wait: outstanding <= N; ties the frags (rule-18-safe). Loads issued
// EARLIER (e.g. gx prefetch) only make the wait more conservative (in-order).
#define WAIT8(N, F)                                                       \
    asm volatile("s_waitcnt vmcnt(" #N ")"                                \
                 : "+v"((F)[0]), "+v"((F)[1]), "+v"((F)[2]),              \
                   "+v"((F)[3]), "+v"((F)[4]), "+v"((F)[5]),              \
                   "+v"((F)[6]), "+v"((F)[7]))

// Z consume: z-weights LDS rows wcol+l16, r-weights rows 32+wcol+l16
#define ZCON(KB, HF)                                                              \
    _Pragma("unroll")                                                             \
    for (int j = 0; j < 8; ++j) {                                                 \
        int kk = (KB) * 8 + j;                                                    \
        frag b0 = *(const frag*)(Wh + (wcol + l16)      * LDW + kk * 32 + quad * 8); \
        frag b1 = *(const frag*)(Wh + (32 + wcol + l16) * LDW + kk * 32 + quad * 8); \
        acc0 = __builtin_amdgcn_mfma_f32_16x16x32_bf16((HF)[j], b0, acc0, 0, 0, 0); \
        acc1 = __builtin_amdgcn_mfma_f32_16x16x32_bf16((HF)[j], b1, acc1, 0, 0, 0); \
    }
// A consume: weights streamed to regs (WF), rh slab (RF)
#define ACON(RF, WF)                                                              \
    _Pragma("unroll")                                                             \
    for (int j = 0; j < 8; ++j)                                                   \
        acc2 = __builtin_amdgcn_mfma_f32_16x16x32_bf16((RF)[j], (WF)[j], acc2, 0, 0, 0);

// ---------------- prep kernels ----------------

__global__ __launch_bounds__(256) void k_gather(const int* __restrict__ x,
                                                const float* __restrict__ embed,
                                                uint16_t* __restrict__ words) {
    int tid = blockIdx.x * 256 + threadIdx.x;
    int row = tid >> 6;
    int c8  = (tid & 63) << 3;
    int tok = x[row];
    float s = (tok > 0) ? 1.f : 0.f;
    const float4* src = (const float4*)(embed + (int64_t)tok * DD + c8);
    float4 v0 = src[0], v1 = src[1];
    float vals[8] = {v0.x, v0.y, v0.z, v0.w, v1.x, v1.y, v1.z, v1.w};
    union { uint16_t u[8]; uint4 q; } pk;
#pragma unroll
    for (int i = 0; i < 8; ++i) pk.u[i] = f2b(vals[i] * s);
    *(uint4*)(words + ((int64_t)row << 9) + c8) = pk.q;
}

__global__ void k_transpose(const float* __restrict__ src, uint16_t* __restrict__ dst,
                            int K, int N) {
    __shared__ float tile[32][33];
    int n0 = blockIdx.x * 32, k0 = blockIdx.y * 32;
    int tx = threadIdx.x, ty = threadIdx.y;   // (32, 8)
#pragma unroll
    for (int i = 0; i < 32; i += 8)
        tile[ty + i][tx] = src[(int64_t)(k0 + ty + i) * N + n0 + tx];
    __syncthreads();
#pragma unroll
    for (int i = 0; i < 32; i += 8)
        dst[(int64_t)(n0 + ty + i) * K + k0 + tx] = f2b(tile[tx][ty + i]);
}

__global__ void k_zero(uint4* p, int n16) {
    int i = blockIdx.x * blockDim.x + threadIdx.x;
    if (i < n16) p[i] = uint4{0u, 0u, 0u, 0u};
}

// ---------------- gx GEMM: 16384 x 3072 x 512 ----------------

__global__ __launch_bounds__(256) void k_gemm_gx(const uint16_t* __restrict__ A,
                                                 const uint16_t* __restrict__ BT,
                                                 const float* __restrict__ bias,
                                                 uint16_t* __restrict__ C) {
    __shared__ uint16_t As[128][72];
    __shared__ uint16_t Bs[128][72];
    int m0 = blockIdx.y * 128;
    int n0 = blockIdx.x * 128;
    int t = threadIdx.x;
    int wave = t >> 6, lane = t & 63, quad = lane >> 4, l16 = lane & 15;
    int wm = (wave & 1) * 64, wn = (wave >> 1) * 64;
    f32x4 acc[4][4] = {};

    int sr = t >> 1;
    int sc = (t & 1) * 32;

    for (int k0 = 0; k0 < DD; k0 += 64) {
        const uint4* ga = (const uint4*)(A + (int64_t)(m0 + sr) * DD + k0 + sc);
        uint4 a0 = ga[0], a1 = ga[1], a2 = ga[2], a3 = ga[3];
        const uint4* gb = (const uint4*)(BT + (int64_t)(n0 + sr) * DD + k0 + sc);
        uint4 b0 = gb[0], b1 = gb[1], b2 = gb[2], b3 = gb[3];
        __syncthreads();
        *(uint4*)&As[sr][sc]      = a0;
        *(uint4*)&As[sr][sc + 8]  = a1;
        *(uint4*)&As[sr][sc + 16] = a2;
        *(uint4*)&As[sr][sc + 24] = a3;
        *(uint4*)&Bs[sr][sc]      = b0;
        *(uint4*)&Bs[sr][sc + 8]  = b1;
        *(uint4*)&Bs[sr][sc + 16] = b2;
        *(uint4*)&Bs[sr][sc + 24] = b3;
        __syncthreads();
#pragma unroll
        for (int kk = 0; kk < 64; kk += 32) {
            frag af[4], bf[4];
#pragma unroll
            for (int mi = 0; mi < 4; ++mi)
                af[mi] = *(const frag*)&As[wm + mi * 16 + l16][kk + quad * 8];
#pragma unroll
            for (int ni = 0; ni < 4; ++ni)
                bf[ni] = *(const frag*)&Bs[wn + ni * 16 + l16][kk + quad * 8];
#pragma unroll
            for (int mi = 0; mi < 4; ++mi)
#pragma unroll
                for (int ni = 0; ni < 4; ++ni)
                    acc[mi][ni] = __builtin_amdgcn_mfma_f32_16x16x32_bf16(
                        af[mi], bf[ni], acc[mi][ni], 0, 0, 0);
        }
    }
#pragma unroll
    for (int ni = 0; ni < 4; ++ni) {
        int col = n0 + wn + ni * 16 + l16;
        float bv = bias[col];
#pragma unroll
        for (int mi = 0; mi < 4; ++mi)
#pragma unroll
            for (int r = 0; r < 4; ++r) {
                int row = m0 + wm + mi * 16 + quad * 4 + r;
                C[(int64_t)row * N3H + col] = f2b(acc[mi][ni][r] + bv);
            }
    }
}

// ---------------- recurrence (R19) ----------------
// grid (8,32): mg = blockIdx.x (-> XCD mg, runtime-verified), jb = blockIdx.y.
// Group mg: batch rows [mg*32, mg*32+32), 32 blocks x 32 cols. Waves: wave&1
// picks row-half (16 rows), wave>>1 picks col-half (16 cols).
// LDS: Wzr[64][1032] bf16 (z cols 0..31 then r cols 0..31) = 129KB.
// Epochs per block slot: after Z(t) -> 2t+1 (rh ready); after A(t) -> 2t+2
// (h(t+1) ready). Z(t>0) waits >=2t; A(t) waits >=2t+1. Static h/rh buffers.

__global__ __launch_bounds__(256, 1) void k_recur(const uint16_t* __restrict__ gx,
                                                  const uint16_t* __restrict__ wht,
                                                  uint16_t* __restrict__ hbuf,
                                                  uint16_t* __restrict__ rhbuf,
                                                  unsigned int* __restrict__ xtab,
                                                  unsigned int* __restrict__ bar,
                                                  float* __restrict__ out) {
    extern __shared__ uint16_t Wh[];           // 64 rows x 1032
    const int LDW = HH + 8;
    int mg = blockIdx.x;        // 0..7 == target XCD
    int jb = blockIdx.y;        // 0..31
    int j0 = jb * 32;
    int m0 = mg * 32;
    int t = threadIdx.x, wave = t >> 6, lane = t & 63, quad = lane >> 4, l16 = lane & 15;
    int wrow = (wave & 1) * 16, wcol = (wave >> 1) * 16;

    // publish my XCD id (sc0sc1: device-visible) before heavy staging
    unsigned int myxcd;
    asm("s_getreg_b32 %0, hwreg(HW_REG_XCC_ID)" : "=s"(myxcd));
    if (t == 0) {
        unsigned int v = myxcd + 1u;
        unsigned int* p = xtab + (mg * 32 + jb);
        asm volatile("global_store_dword %0, %1, off sc0 sc1" :: "v"(p), "v"(v) : "memory");
    }

    // stage W_zr: LDS row i<32 <- wht row (j0+i) [z]; i>=32 <- HH + j0 + i-32 [r]
    for (int c = t; c < 64 * 128; c += 256) {
        int row = c >> 7, off = (c & 127) << 3;
        int o = (row < 32) ? (j0 + row) : (HH + j0 + row - 32);
        *(uint4*)(Wh + row * LDW + off) = *(const uint4*)(wht + (int64_t)o * HH + off);
    }
    __syncthreads();

    // classify: group pure iff all 32 peer xtab entries equal AND == my XCD.
    bool pure;
    {
        const unsigned int* xs = xtab + (mg * 32 + (lane & 31));
        unsigned int tv = 0;
        long guard = 0;
        for (;;) {
            asm volatile("global_load_dword %0, %1, off sc0 sc1\n\ts_waitcnt vmcnt(0)"
                         : "=v"(tv) : "v"(xs) : "memory");
            if (__all((int)(tv >= 1u))) break;
            __builtin_amdgcn_s_sleep(4);
            if (++guard > (1L << 15)) break;
        }
        pure = __all((int)(tv == myxcd + 1u));
    }

    float hp[4]   = {0.f, 0.f, 0.f, 0.f};
    float zg[4];
    float osum[4] = {0.f, 0.f, 0.f, 0.f};
    int brow = m0 + wrow + quad * 4;
    int jcol = j0 + wcol + l16;
    const int jc4 = j0 + wcol + (l16 & ~3);
    unsigned int* eslot = bar + (size_t)(mg * 32 + jb) * 64;        // 256B-strided

    const int64_t arow = (int64_t)(m0 + wrow + l16) * HH + quad * 8;
    const uint16_t* harow  = hbuf  + arow;
    const uint16_t* rharow = rhbuf + arow;
    // per-wave W_a fragment base: weight row (col) = 2*HH + j0 + wcol + l16
    const uint16_t* wabase = wht + (int64_t)(2 * HH + j0 + wcol + l16) * HH + quad * 8;

    // arrive: __syncthreads drains this block's data stores (vmcnt(0) before
    // s_barrier), then t==0 publishes the epoch. sc0 in pure mode (L2 is the
    // group's coherence point); sc0sc1 otherwise.
    auto arrive = [&](unsigned int ep) {
        __syncthreads();
        if (t == 0) {
            if (pure) asm volatile("global_store_dword %0, %1, off sc0"
                                   :: "v"(eslot), "v"(ep) : "memory");
            else      asm volatile("global_store_dword %0, %1, off sc0 sc1"
                                   :: "v"(eslot), "v"(ep) : "memory");
        }
    };
    // wait: wave0 polls the 32 peer slots; lanes duplicate via lane&31.
    auto wait_ep = [&](unsigned int ep) {
        if (wave == 0) {
            const unsigned int* slot = bar + (size_t)(mg * 32 + (lane & 31)) * 64;
            long guard = 0;
            for (;;) {
                unsigned int v;
                if (pure) asm volatile("global_load_dword %0, %1, off sc0\n\ts_waitcnt vmcnt(0)"
                                       : "=v"(v) : "v"(slot) : "memory");
                else      asm volatile("global_load_dword %0, %1, off sc0 sc1\n\ts_waitcnt vmcnt(0)"
                                       : "=v"(v) : "v"(slot) : "memory");
                if (__all((int)(v >= ep))) break;
                __builtin_amdgcn_s_sleep(1);
                if (++guard > (1L << 13)) break;   // fail fast (absmax), never wedge
            }
        }
        __syncthreads();
    };
    // pack lanes l16^1,l16^2 -> u64 (4 cols); (l16%4==0) lane stores it.
    auto store4 = [&](uint16_t* base, int r, uint32_t mine) {
        uint32_t p2 = mine | (((uint32_t)__shfl_xor((int)mine, 1)) << 16);
        uint32_t hi = (uint32_t)__shfl_xor((int)p2, 2);
        if ((l16 & 3) == 0) {
            uint64_t p4 = (uint64_t)p2 | ((uint64_t)hi << 32);
            uint64_t* dst = (uint64_t*)base + (int64_t)(brow + r) * (HH / 4) + (jc4 >> 2);
            if (pure) asm volatile("global_store_dwordx2 %0, %1, off sc0"
                                   :: "v"(dst), "v"(p4) : "memory");
            else      asm volatile("global_store_dwordx2 %0, %1, off sc0 sc1"
                                   :: "v"(dst), "v"(p4) : "memory");
        }
    };
    auto slab8 = [&](const uint16_t* p, frag* f) {
        if (pure) load8_l2(p, f); else load8_l3(p, f);
    };

    for (int step = 0; step < TT; ++step) {
        // gx prefetch (immutable, cached) - hides under the epoch poll
        uint16_t gzv[4], grv[4], gav[4];
        {
            const uint16_t* gxrow = gx + (int64_t)step * BB * N3H;
#pragma unroll
            for (int r = 0; r < 4; ++r) {
                const uint16_t* g = gxrow + (int64_t)(brow + r) * N3H + jcol;
                gzv[r] = g[0]; grv[r] = g[HH]; gav[r] = g[2 * HH];
            }
        }

        if (step > 0) wait_ep(2u * (unsigned)step);

        // ---- phase Z: h @ W_zr (acc0 = z, acc1 = r), depth-1 pipeline ----
        {
            f32x4 acc0 = {}, acc1 = {};
            frag h0[8], h1[8], h2[8], h3[8];
            slab8(harow,       h0);
            slab8(harow + 256, h1);
            WAIT8(8, h0); ZCON(0, h0);
            slab8(harow + 512, h2);
            WAIT8(8, h1); ZCON(1, h1);
            slab8(harow + 768, h3);
            WAIT8(8, h2); ZCON(2, h2);
            WAIT8(0, h3); ZCON(3, h3);
#pragma unroll
            for (int r = 0; r < 4; ++r) {
                float zp = b2f(gzv[r]) + acc0[r];        // bias folded into gx
                float rp = b2f(grv[r]) + acc1[r];
                float z  = 1.f / (1.f + __expf(-zp));
                float rg = 1.f / (1.f + __expf(-rp));
                zg[r] = z;
                store4(rhbuf, r, (uint32_t)f2b(rg * hp[r]));
            }
        }
        arrive(2u * (unsigned)step + 1u);
        wait_ep(2u * (unsigned)step + 1u);

        // ---- phase A: (r*h) @ W_a, weights streamed from L2, depth-1 ----
        {
            f32x4 acc2 = {};
            frag r0[8], r1[8], r2[8], r3[8];
            frag w0[8], w1[8], w2[8], w3[8];
            slab8(rharow,        r0); load8_c(wabase,       w0);
            slab8(rharow + 256,  r1); load8_c(wabase + 256, w1);
            WAIT8(16, r0); WAIT8(16, w0); ACON(r0, w0);
            slab8(rharow + 512,  r2); load8_c(wabase + 512, w2);
            WAIT8(16, r1); WAIT8(16, w1); ACON(r1, w1);
            slab8(rharow + 768,  r3); load8_c(wabase + 768, w3);
            WAIT8(16, r2); WAIT8(16, w2); ACON(r2, w2);
            WAIT8(0,  r3); WAIT8(0,  w3); ACON(r3, w3);
#pragma unroll
            for (int r = 0; r < 4; ++r) {
                float a  = tanhf(b2f(gav[r]) + acc2[r]);
                float hn = (1.f - zg[r]) * hp[r] + zg[r] * a;
                osum[r] += hn;
                hp[r] = hn;
                store4(hbuf, r, (uint32_t)f2b(hn));
            }
        }
        arrive(2u * (unsigned)step + 2u);
    }
#pragma unroll
    for (int r = 0; r < 4; ++r)
        out[(int64_t)(brow + r) * HH + jcol] = osum[r];
}

// ---------------- launch ----------------

extern "C" void kernel_launch(void* const* d_in, const int* in_sizes, int n_in,
                              void* d_out, int out_size, void* d_ws, size_t ws_size,
                              hipStream_t stream) {
    const int*   x     = (const int*)d_in[0];
    const float* embed = (const float*)d_in[1];
    const float* w_i   = (const float*)d_in[2];
    const float* w_h   = (const float*)d_in[3];
    const float* bias  = (const float*)d_in[4];
    float* out = (float*)d_out;

    char* ws = (char*)d_ws;
    uint16_t* gx    = (uint16_t*)(ws);                 // 16384*3072*2 = 100663296
    uint16_t* wit   = (uint16_t*)(ws + 100663296);     // 3072*512*2  =   3145728
    uint16_t* wht   = (uint16_t*)(ws + 103809024);     // 3072*1024*2 =   6291456
    uint16_t* words = (uint16_t*)(ws + 110100480);     // 16384*512*2 =  16777216
    uint16_t* hbuf  = (uint16_t*)(ws + 126877696);     // 256*1024*2  =    524288
    uint16_t* rhbuf = (uint16_t*)(ws + 127401984);     // 256*1024*2  =    524288
    unsigned int* xtab = (unsigned int*)(ws + 127926272);  // 256*4 = 1KB (pad 4KB)
    unsigned int* bar  = (unsigned int*)(ws + 127930368);  // 256 slots * 256B = 64KB

    k_gather<<<4096, 256, 0, stream>>>(x, embed, words);
    k_transpose<<<dim3(96, 16), dim3(32, 8), 0, stream>>>(w_i, wit, DD, N3H);
    k_transpose<<<dim3(96, 32), dim3(32, 8), 0, stream>>>(w_h, wht, HH, N3H);
    // zero hbuf + rhbuf + xtab + bar (contiguous 1048576 + 4096 + 65536)
    k_zero<<<273, 256, 0, stream>>>((uint4*)(ws + 126877696), (1048576 + 4096 + 65536) / 16);
    k_gemm_gx<<<dim3(24, 128), 256, 0, stream>>>(words, wit, bias, gx);
    k_recur<<<dim3(8, 32), 256, 64 * (HH + 8) * 2, stream>>>(gx, wht, hbuf, rhbuf,
                                                             xtab, bar, out);
}